// Round 6
// baseline (109.595 us; speedup 1.0000x reference)
//
#include <hip/hip_runtime.h>

// Problem constants (from reference)
#define Bv   8
#define Kv   2048
#define Sv   1024
#define Hv   256      // elements per row; 64 lanes x 4 each
#define Wv   24
#define WINv 3

#define NSPAN (Bv * Kv)

__device__ __forceinline__ float bf16_to_f32(unsigned short u) {
    union { unsigned int i; float f; } c;
    c.i = ((unsigned int)u) << 16;
    return c.f;
}

// One wave (64 lanes) per span; lane owns elements [4*lane, 4*lane+4).
// Block = 256 threads = 4 waves = 4 spans. Output fp32 [B,K,3H].
// token width (bf16 vs fp32), ids width (i32 vs i64), mask width
// (u8/f32/i32/i64) are all sniffed at runtime from data patterns.
__global__ __launch_bounds__(256) void span_rep_kernel(
    const void* __restrict__ token_reps,
    const int* __restrict__ span_ids,
    const void* __restrict__ span_masks,
    float* __restrict__ out)
{
    __shared__ int s_tok32;   // 1 if token_reps is fp32, 0 if bf16
    __shared__ int s_ids64;   // 1 if span_ids is int64
    __shared__ int s_maskw;   // 0 uchar, 1 int32, 2 int64, 3 fp32

    if (threadIdx.x == 0) {
        // --- token width: even-index ushorts of bf16 normals have exponent
        // field in a narrow band; of fp32 they are random mantissa bits.
        const unsigned short* tu = (const unsigned short*)token_reps;
        int votes = 0;
        for (int i = 0; i < 64; ++i) {
            int e = (tu[2 * i] >> 7) & 0xFF;
            if (e >= 96 && e <= 144) votes++;
        }
        s_tok32 = (votes >= 56) ? 0 : 1;

        // --- ids width: int32-interleaved => odd slots are ends (>=1);
        // int64 => odd int32 slots are hi-words of values <1024 => zero.
        int odd_or = span_ids[1] | span_ids[3] | span_ids[5] | span_ids[7];
        s_ids64 = (odd_or == 0) ? 1 : 0;

        // --- mask width from nonzero byte positions (~90% True density):
        // uchar: nonzeros at i%4==1 (and elsewhere)
        // fp32 (1.0f=00,00,80,3F): nonzeros only at i%4==2,3
        // int32: nonzeros only at i%4==0 (incl i%8==4)
        // int64: nonzeros only at i%8==0
        const unsigned char* mb = (const unsigned char*)span_masks;
        int nz1 = 0, nz23 = 0, nz84 = 0;
        for (int i = 0; i < 128; ++i) {
            if (mb[i]) {
                int m4 = i & 3;
                if (m4 == 1) nz1 = 1;
                else if (m4 == 2 || m4 == 3) nz23 = 1;
                else if (i & 7) nz84 = 1;    // i%8==4
            }
        }
        s_maskw = nz1 ? 0 : (nz23 ? 3 : (nz84 ? 1 : 2));
    }
    __syncthreads();

    const int span = blockIdx.x * 4 + (threadIdx.x >> 6);
    const int lane = threadIdx.x & 63;

    float4* out4 = (float4*)(out + (size_t)span * (3 * Hv)) + lane;

    // --- decode mask (wave-uniform) ---
    int mv;
    if (s_maskw == 0)      mv = ((const unsigned char*)span_masks)[span];
    else if (s_maskw == 1) mv = ((const int*)span_masks)[span];
    else if (s_maskw == 2) mv = ((const int*)span_masks)[2 * span];
    else                   mv = (((const float*)span_masks)[span] != 0.0f);

    // --- decode ids (wave-uniform) ---
    int start, end;
    if (!s_ids64) {
        start = span_ids[2 * span];
        end   = span_ids[2 * span + 1];
    } else {
        start = span_ids[4 * span];       // lo word of int64 elem 2*span
        end   = span_ids[4 * span + 2];   // lo word of int64 elem 2*span+1
    }
    const int w = end - start;

    // invalid span or insane decode -> zeros (keeps failures finite/diagnosable)
    if (mv == 0 || w < 1 || w > Wv || start < 0 || end > Sv) {
        float4 z = make_float4(0.f, 0.f, 0.f, 0.f);
        out4[0]       = z;   // start section
        out4[Hv / 4]  = z;   // inner section
        out4[Hv / 2]  = z;   // end section
        return;
    }

    const int b = span >> 11;                    // span / K
    const size_t row0 = ((size_t)b * Sv + start) * Hv;

    float s0 = -INFINITY, s1 = -INFINITY, s2 = -INFINITY, s3 = -INFINITY;
    float e0 = -INFINITY, e1 = -INFINITY, e2 = -INFINITY, e3 = -INFINITY;
    float i0 = -INFINITY, i1 = -INFINITY, i2 = -INFINITY, i3 = -INFINITY;

    const int  scut      = (w < WINv) ? w : WINv;            // start rows [0, scut)
    const int  ecut      = (w - WINv > 0) ? (w - WINv) : 0;  // end rows [ecut, w)
    const bool has_inner = (w > 2 * WINv);                   // inner rows [WIN, w-WIN)

    // Wave-uniform predicates; coalesced loads (1KB/wave/row fp32, 512B bf16).
    for (int r = 0; r < w; ++r) {
        float v0, v1, v2, v3;
        if (s_tok32) {
            const float4* p = (const float4*)((const float*)token_reps + row0) +
                              (size_t)r * (Hv / 4) + lane;
            float4 f = *p;
            v0 = f.x; v1 = f.y; v2 = f.z; v3 = f.w;
        } else {
            const unsigned short* p = (const unsigned short*)token_reps + row0 +
                                      (size_t)r * Hv + lane * 4;
            ushort4 u = *(const ushort4*)p;
            v0 = bf16_to_f32(u.x); v1 = bf16_to_f32(u.y);
            v2 = bf16_to_f32(u.z); v3 = bf16_to_f32(u.w);
        }
        if (r < scut) {
            s0 = fmaxf(s0, v0); s1 = fmaxf(s1, v1);
            s2 = fmaxf(s2, v2); s3 = fmaxf(s3, v3);
        }
        if (r >= ecut) {
            e0 = fmaxf(e0, v0); e1 = fmaxf(e1, v1);
            e2 = fmaxf(e2, v2); e3 = fmaxf(e3, v3);
        }
        if (has_inner && r >= WINv && r < w - WINv) {
            i0 = fmaxf(i0, v0); i1 = fmaxf(i1, v1);
            i2 = fmaxf(i2, v2); i3 = fmaxf(i3, v3);
        }
    }
    if (!has_inner) { i0 = s0; i1 = s1; i2 = s2; i3 = s3; }  // no_inner -> start

    out4[0]      = make_float4(s0, s1, s2, s3);   // start
    out4[Hv / 4] = make_float4(i0, i1, i2, i3);   // inner
    out4[Hv / 2] = make_float4(e0, e1, e2, e3);   // end
}

extern "C" void kernel_launch(void* const* d_in, const int* in_sizes, int n_in,
                              void* d_out, int out_size, void* d_ws, size_t ws_size,
                              hipStream_t stream) {
    // Identify inputs by element count (robust to ordering changes):
    // token_reps = 2,097,152; span_ids = 65,536; span_masks = 16,384.
    const void* token_reps = d_in[0];
    const int*  span_ids   = (const int*)d_in[1];
    const void* span_masks = d_in[2];
    for (int i = 0; i < n_in; ++i) {
        if (in_sizes[i] == Bv * Sv * Hv)      token_reps = d_in[i];
        else if (in_sizes[i] == Bv * Kv * 2)  span_ids   = (const int*)d_in[i];
        else if (in_sizes[i] == Bv * Kv)      span_masks = d_in[i];
    }
    float* out = (float*)d_out;

    // 16384 spans, 4 spans (waves) per 256-thread block
    dim3 grid(NSPAN / 4);
    dim3 block(256);
    span_rep_kernel<<<grid, block, 0, stream>>>(token_reps, span_ids, span_masks, out);
}

// Round 7
// 91.001 us; speedup vs baseline: 1.2043x; 1.2043x over previous
//
#include <hip/hip_runtime.h>

// Problem constants (from reference)
#define Bv   8
#define Kv   2048
#define Sv   1024
#define Hv   256      // elements per row; 64 lanes x 4 each
#define Wv   24
#define WINv 3
#define RB   8        // row batch: 8 outstanding loads per wave

#define NSPAN (Bv * Kv)

__device__ __forceinline__ float bf16_to_f32(unsigned short u) {
    union { unsigned int i; float f; } c;
    c.i = ((unsigned int)u) << 16;
    return c.f;
}

// One wave (64 lanes) per span; lane owns elements [4*lane, 4*lane+4).
// Block = 256 threads = 4 waves = 4 spans. Output fp32 [B,K,3H].
// token width (bf16 vs fp32), ids width (i32 vs i64), mask width
// (u8/f32/i32/i64) sniffed at runtime from data patterns (wave-0 ballots).
__global__ __launch_bounds__(256) void span_rep_kernel(
    const void* __restrict__ token_reps,
    const int* __restrict__ span_ids,
    const void* __restrict__ span_masks,
    float* __restrict__ out)
{
    __shared__ int s_tok32;   // 1 if token_reps is fp32, 0 if bf16
    __shared__ int s_ids64;   // 1 if span_ids is int64
    __shared__ int s_maskw;   // 0 uchar, 1 int32, 2 int64, 3 fp32

    const int tid = threadIdx.x;
    if (tid < 64) {
        // token width: even-index ushorts of bf16 normals have exponent
        // field in a narrow band; of fp32 they are random mantissa bits.
        const unsigned short* tu = (const unsigned short*)token_reps;
        int e = (tu[2 * tid] >> 7) & 0xFF;
        unsigned long long votes = __ballot(e >= 96 && e <= 144);

        // mask width from nonzero byte positions (~90% True density).
        // (tid and tid+64 share tid%8, so classes merge.)
        const unsigned char* mb = (const unsigned char*)span_masks;
        unsigned char bnz = mb[tid] | mb[tid + 64];
        int m4 = tid & 3;
        unsigned long long z1  = __ballot(bnz && m4 == 1);                    // uchar
        unsigned long long z23 = __ballot(bnz && (m4 == 2 || m4 == 3));       // fp32
        unsigned long long z84 = __ballot(bnz && m4 == 0 && (tid & 7) == 4);  // int32

        if (tid == 0) {
            s_tok32 = (__popcll(votes) >= 56) ? 0 : 1;
            s_maskw = z1 ? 0 : (z23 ? 3 : (z84 ? 1 : 2));
            // ids: int32-interleaved => odd slots are ends (>=1);
            // int64 => odd int32 slots are hi-words of values <1024 => zero.
            int odd_or = span_ids[1] | span_ids[3] | span_ids[5] | span_ids[7];
            s_ids64 = (odd_or == 0) ? 1 : 0;
        }
    }
    __syncthreads();

    const int span = blockIdx.x * 4 + (tid >> 6);
    const int lane = tid & 63;

    float4* out4 = (float4*)(out + (size_t)span * (3 * Hv)) + lane;

    // --- decode mask (wave-uniform) ---
    int mv;
    if (s_maskw == 0)      mv = ((const unsigned char*)span_masks)[span];
    else if (s_maskw == 1) mv = ((const int*)span_masks)[span];
    else if (s_maskw == 2) mv = ((const int*)span_masks)[2 * span];
    else                   mv = (((const float*)span_masks)[span] != 0.0f);

    // --- decode ids (wave-uniform) ---
    int start, end;
    if (!s_ids64) {
        start = span_ids[2 * span];
        end   = span_ids[2 * span + 1];
    } else {
        start = span_ids[4 * span];       // lo word of int64 elem 2*span
        end   = span_ids[4 * span + 2];   // lo word of int64 elem 2*span+1
    }
    const int w = end - start;

    // invalid span or insane decode -> zeros (keeps failures finite/diagnosable)
    if (mv == 0 || w < 1 || w > Wv || start < 0 || end > Sv) {
        float4 z = make_float4(0.f, 0.f, 0.f, 0.f);
        out4[0]       = z;   // start section
        out4[Hv / 4]  = z;   // inner section
        out4[Hv / 2]  = z;   // end section
        return;
    }

    const int b = span >> 11;                    // span / K
    const size_t row0 = ((size_t)b * Sv + start) * Hv;

    float s0 = -INFINITY, s1 = -INFINITY, s2 = -INFINITY, s3 = -INFINITY;
    float e0 = -INFINITY, e1 = -INFINITY, e2 = -INFINITY, e3 = -INFINITY;
    float i0 = -INFINITY, i1 = -INFINITY, i2 = -INFINITY, i3 = -INFINITY;

    const int  scut      = (w < WINv) ? w : WINv;            // start rows [0, scut)
    const int  ecut      = (w - WINv > 0) ? (w - WINv) : 0;  // end rows [ecut, w)
    const bool has_inner = (w > 2 * WINv);                   // inner rows [WIN, w-WIN)
    const int  icut      = w - WINv;

    // Batched row loop: issue RB independent loads into buf[], then reduce.
    // buf[j] consumed in issue order -> compiler emits incremental vmcnt
    // waits -> RB outstanding loads per wave (MLP fix for latency bound).
    // All guards are wave-uniform (w uniform per span).
    if (s_tok32) {
        const float4* tp = (const float4*)((const float*)token_reps + row0) + lane;
        for (int r0 = 0; r0 < w; r0 += RB) {
            const int n = ((w - r0) < RB) ? (w - r0) : RB;
            float4 buf[RB];
            #pragma unroll
            for (int j = 0; j < RB; ++j)
                if (j < n) buf[j] = tp[(size_t)(r0 + j) * (Hv / 4)];
            #pragma unroll
            for (int j = 0; j < RB; ++j) {
                if (j < n) {
                    const int r = r0 + j;
                    float4 f = buf[j];
                    if (r < scut) {
                        s0 = fmaxf(s0, f.x); s1 = fmaxf(s1, f.y);
                        s2 = fmaxf(s2, f.z); s3 = fmaxf(s3, f.w);
                    }
                    if (r >= ecut) {
                        e0 = fmaxf(e0, f.x); e1 = fmaxf(e1, f.y);
                        e2 = fmaxf(e2, f.z); e3 = fmaxf(e3, f.w);
                    }
                    if (has_inner && r >= WINv && r < icut) {
                        i0 = fmaxf(i0, f.x); i1 = fmaxf(i1, f.y);
                        i2 = fmaxf(i2, f.z); i3 = fmaxf(i3, f.w);
                    }
                }
            }
        }
    } else {
        const unsigned short* tp = (const unsigned short*)token_reps + row0 + lane * 4;
        for (int r0 = 0; r0 < w; r0 += RB) {
            const int n = ((w - r0) < RB) ? (w - r0) : RB;
            ushort4 buf[RB];
            #pragma unroll
            for (int j = 0; j < RB; ++j)
                if (j < n) buf[j] = *(const ushort4*)(tp + (size_t)(r0 + j) * Hv);
            #pragma unroll
            for (int j = 0; j < RB; ++j) {
                if (j < n) {
                    const int r = r0 + j;
                    float f0 = bf16_to_f32(buf[j].x), f1 = bf16_to_f32(buf[j].y);
                    float f2 = bf16_to_f32(buf[j].z), f3 = bf16_to_f32(buf[j].w);
                    if (r < scut) {
                        s0 = fmaxf(s0, f0); s1 = fmaxf(s1, f1);
                        s2 = fmaxf(s2, f2); s3 = fmaxf(s3, f3);
                    }
                    if (r >= ecut) {
                        e0 = fmaxf(e0, f0); e1 = fmaxf(e1, f1);
                        e2 = fmaxf(e2, f2); e3 = fmaxf(e3, f3);
                    }
                    if (has_inner && r >= WINv && r < icut) {
                        i0 = fmaxf(i0, f0); i1 = fmaxf(i1, f1);
                        i2 = fmaxf(i2, f2); i3 = fmaxf(i3, f3);
                    }
                }
            }
        }
    }
    if (!has_inner) { i0 = s0; i1 = s1; i2 = s2; i3 = s3; }  // no_inner -> start

    out4[0]      = make_float4(s0, s1, s2, s3);   // start
    out4[Hv / 4] = make_float4(i0, i1, i2, i3);   // inner
    out4[Hv / 2] = make_float4(e0, e1, e2, e3);   // end
}

extern "C" void kernel_launch(void* const* d_in, const int* in_sizes, int n_in,
                              void* d_out, int out_size, void* d_ws, size_t ws_size,
                              hipStream_t stream) {
    // Identify inputs by element count (robust to ordering changes):
    // token_reps = 2,097,152; span_ids = 65,536; span_masks = 16,384.
    const void* token_reps = d_in[0];
    const int*  span_ids   = (const int*)d_in[1];
    const void* span_masks = d_in[2];
    for (int i = 0; i < n_in; ++i) {
        if (in_sizes[i] == Bv * Sv * Hv)      token_reps = d_in[i];
        else if (in_sizes[i] == Bv * Kv * 2)  span_ids   = (const int*)d_in[i];
        else if (in_sizes[i] == Bv * Kv)      span_masks = d_in[i];
    }
    float* out = (float*)d_out;

    // 16384 spans, 4 spans (waves) per 256-thread block
    dim3 grid(NSPAN / 4);
    dim3 block(256);
    span_rep_kernel<<<grid, block, 0, stream>>>(token_reps, span_ids, span_masks, out);
}

// Round 8
// 87.846 us; speedup vs baseline: 1.2476x; 1.0359x over previous
//
#include <hip/hip_runtime.h>

// Problem constants (from reference)
#define Bv   8
#define Kv   2048
#define Sv   1024
#define Hv   256      // elements per row; 64 lanes x 4 each
#define Wv   24
#define WINv 3
#define RB   8        // row batch: 8 outstanding loads per wave

#define NSPAN (Bv * Kv)

__device__ __forceinline__ float bf16_to_f32(unsigned short u) {
    union { unsigned int i; float f; } c;
    c.i = ((unsigned int)u) << 16;
    return c.f;
}

// One wave (64 lanes) per span; lane owns elements [4*lane, 4*lane+4).
// Block = 256 threads = 4 waves = 4 spans. Output fp32 [B,K,3H].
// XCD swizzle: b = blockIdx&7, so under round-robin block->XCD dispatch each
// XCD reads only its own batch's 1 MB of token_reps (L2-resident, 4 MiB/XCD).
// token width (bf16 vs fp32), ids width (i32 vs i64), mask width
// (u8/f32/i32/i64) sniffed at runtime from data patterns (wave-0 ballots).
__global__ __launch_bounds__(256) void span_rep_kernel(
    const void* __restrict__ token_reps,
    const int* __restrict__ span_ids,
    const void* __restrict__ span_masks,
    float* __restrict__ out)
{
    __shared__ int s_tok32;   // 1 if token_reps is fp32, 0 if bf16
    __shared__ int s_ids64;   // 1 if span_ids is int64
    __shared__ int s_maskw;   // 0 uchar, 1 int32, 2 int64, 3 fp32

    const int tid = threadIdx.x;
    if (tid < 64) {
        // token width: even-index ushorts of bf16 normals have exponent
        // field in a narrow band; of fp32 they are random mantissa bits.
        const unsigned short* tu = (const unsigned short*)token_reps;
        int e = (tu[2 * tid] >> 7) & 0xFF;
        unsigned long long votes = __ballot(e >= 96 && e <= 144);

        // mask width from nonzero byte positions (~90% True density).
        // (tid and tid+64 share tid%8, so classes merge.)
        const unsigned char* mb = (const unsigned char*)span_masks;
        unsigned char bnz = mb[tid] | mb[tid + 64];
        int m4 = tid & 3;
        unsigned long long z1  = __ballot(bnz && m4 == 1);                    // uchar
        unsigned long long z23 = __ballot(bnz && (m4 == 2 || m4 == 3));       // fp32
        unsigned long long z84 = __ballot(bnz && m4 == 0 && (tid & 7) == 4);  // int32

        if (tid == 0) {
            s_tok32 = (__popcll(votes) >= 56) ? 0 : 1;
            s_maskw = z1 ? 0 : (z23 ? 3 : (z84 ? 1 : 2));
            // ids: int32-interleaved => odd slots are ends (>=1);
            // int64 => odd int32 slots are hi-words of values <1024 => zero.
            int odd_or = span_ids[1] | span_ids[3] | span_ids[5] | span_ids[7];
            s_ids64 = (odd_or == 0) ? 1 : 0;
        }
    }
    __syncthreads();

    // XCD-locality swizzle: batch = blockIdx&7 (one batch per XCD),
    // k = (blockIdx>>3)*4 + wave. 4096 blocks cover all 16384 spans.
    const int b    = blockIdx.x & 7;
    const int k    = ((blockIdx.x >> 3) << 2) + (tid >> 6);
    const int span = b * Kv + k;
    const int lane = tid & 63;

    float4* out4 = (float4*)(out + (size_t)span * (3 * Hv)) + lane;

    // --- decode mask (wave-uniform) ---
    int mv;
    if (s_maskw == 0)      mv = ((const unsigned char*)span_masks)[span];
    else if (s_maskw == 1) mv = ((const int*)span_masks)[span];
    else if (s_maskw == 2) mv = ((const int*)span_masks)[2 * span];
    else                   mv = (((const float*)span_masks)[span] != 0.0f);

    // --- decode ids (wave-uniform) ---
    int start, end;
    if (!s_ids64) {
        start = span_ids[2 * span];
        end   = span_ids[2 * span + 1];
    } else {
        start = span_ids[4 * span];       // lo word of int64 elem 2*span
        end   = span_ids[4 * span + 2];   // lo word of int64 elem 2*span+1
    }
    const int w = end - start;

    // invalid span or insane decode -> zeros (keeps failures finite/diagnosable)
    if (mv == 0 || w < 1 || w > Wv || start < 0 || end > Sv) {
        float4 z = make_float4(0.f, 0.f, 0.f, 0.f);
        out4[0]       = z;   // start section
        out4[Hv / 4]  = z;   // inner section
        out4[Hv / 2]  = z;   // end section
        return;
    }

    const size_t row0 = ((size_t)b * Sv + start) * Hv;

    float s0 = -INFINITY, s1 = -INFINITY, s2 = -INFINITY, s3 = -INFINITY;
    float e0 = -INFINITY, e1 = -INFINITY, e2 = -INFINITY, e3 = -INFINITY;
    float i0 = -INFINITY, i1 = -INFINITY, i2 = -INFINITY, i3 = -INFINITY;

    const int  scut      = (w < WINv) ? w : WINv;            // start rows [0, scut)
    const int  ecut      = (w - WINv > 0) ? (w - WINv) : 0;  // end rows [ecut, w)
    const bool has_inner = (w > 2 * WINv);                   // inner rows [WIN, w-WIN)
    const int  icut      = w - WINv;

    // Batched row loop: issue RB independent loads into buf[], then reduce.
    // buf[j] consumed in issue order -> compiler emits incremental vmcnt
    // waits -> RB outstanding loads per wave (MLP for latency hiding).
    // All guards are wave-uniform (w uniform per span).
    if (s_tok32) {
        const float4* tp = (const float4*)((const float*)token_reps + row0) + lane;
        for (int r0 = 0; r0 < w; r0 += RB) {
            const int n = ((w - r0) < RB) ? (w - r0) : RB;
            float4 buf[RB];
            #pragma unroll
            for (int j = 0; j < RB; ++j)
                if (j < n) buf[j] = tp[(size_t)(r0 + j) * (Hv / 4)];
            #pragma unroll
            for (int j = 0; j < RB; ++j) {
                if (j < n) {
                    const int r = r0 + j;
                    float4 f = buf[j];
                    if (r < scut) {
                        s0 = fmaxf(s0, f.x); s1 = fmaxf(s1, f.y);
                        s2 = fmaxf(s2, f.z); s3 = fmaxf(s3, f.w);
                    }
                    if (r >= ecut) {
                        e0 = fmaxf(e0, f.x); e1 = fmaxf(e1, f.y);
                        e2 = fmaxf(e2, f.z); e3 = fmaxf(e3, f.w);
                    }
                    if (has_inner && r >= WINv && r < icut) {
                        i0 = fmaxf(i0, f.x); i1 = fmaxf(i1, f.y);
                        i2 = fmaxf(i2, f.z); i3 = fmaxf(i3, f.w);
                    }
                }
            }
        }
    } else {
        const unsigned short* tp = (const unsigned short*)token_reps + row0 + lane * 4;
        for (int r0 = 0; r0 < w; r0 += RB) {
            const int n = ((w - r0) < RB) ? (w - r0) : RB;
            ushort4 buf[RB];
            #pragma unroll
            for (int j = 0; j < RB; ++j)
                if (j < n) buf[j] = *(const ushort4*)(tp + (size_t)(r0 + j) * Hv);
            #pragma unroll
            for (int j = 0; j < RB; ++j) {
                if (j < n) {
                    const int r = r0 + j;
                    float f0 = bf16_to_f32(buf[j].x), f1 = bf16_to_f32(buf[j].y);
                    float f2 = bf16_to_f32(buf[j].z), f3 = bf16_to_f32(buf[j].w);
                    if (r < scut) {
                        s0 = fmaxf(s0, f0); s1 = fmaxf(s1, f1);
                        s2 = fmaxf(s2, f2); s3 = fmaxf(s3, f3);
                    }
                    if (r >= ecut) {
                        e0 = fmaxf(e0, f0); e1 = fmaxf(e1, f1);
                        e2 = fmaxf(e2, f2); e3 = fmaxf(e3, f3);
                    }
                    if (has_inner && r >= WINv && r < icut) {
                        i0 = fmaxf(i0, f0); i1 = fmaxf(i1, f1);
                        i2 = fmaxf(i2, f2); i3 = fmaxf(i3, f3);
                    }
                }
            }
        }
    }
    if (!has_inner) { i0 = s0; i1 = s1; i2 = s2; i3 = s3; }  // no_inner -> start

    out4[0]      = make_float4(s0, s1, s2, s3);   // start
    out4[Hv / 4] = make_float4(i0, i1, i2, i3);   // inner
    out4[Hv / 2] = make_float4(e0, e1, e2, e3);   // end
}

extern "C" void kernel_launch(void* const* d_in, const int* in_sizes, int n_in,
                              void* d_out, int out_size, void* d_ws, size_t ws_size,
                              hipStream_t stream) {
    // Identify inputs by element count (robust to ordering changes):
    // token_reps = 2,097,152; span_ids = 65,536; span_masks = 16,384.
    const void* token_reps = d_in[0];
    const int*  span_ids   = (const int*)d_in[1];
    const void* span_masks = d_in[2];
    for (int i = 0; i < n_in; ++i) {
        if (in_sizes[i] == Bv * Sv * Hv)      token_reps = d_in[i];
        else if (in_sizes[i] == Bv * Kv * 2)  span_ids   = (const int*)d_in[i];
        else if (in_sizes[i] == Bv * Kv)      span_masks = d_in[i];
    }
    float* out = (float*)d_out;

    // 16384 spans, 4 spans (waves) per 256-thread block
    dim3 grid(NSPAN / 4);
    dim3 block(256);
    span_rep_kernel<<<grid, block, 0, stream>>>(token_reps, span_ids, span_masks, out);
}